// Round 6
// baseline (46.394 us; speedup 1.0000x reference)
//
#include <hip/hip_runtime.h>

#define C_LEAF 2048
#define E_DIM  12
#define BLOCK  256

__global__ __launch_bounds__(BLOCK) void hll_per_sample(
    const float* __restrict__ inputs,    // [B, C_LEAF]
    const int*   __restrict__ target,    // [B]
    const float* __restrict__ onum,      // [C_ALL, C_LEAF, E]
    const float* __restrict__ oden,      // [C_ALL, C_LEAF, E]
    const float* __restrict__ weights,   // [C_ALL, E]
    float*       __restrict__ per_sample // [B]
) {
    const int b = blockIdx.x;
    const int t = target[b];

    const float* __restrict__ xrow = inputs + (size_t)b * C_LEAF;
    const float* __restrict__ nrow = onum + (size_t)t * C_LEAF * E_DIM;
    const float* __restrict__ drow = oden + (size_t)t * C_LEAF * E_DIM;

    float accn[E_DIM], accd[E_DIM];
#pragma unroll
    for (int e = 0; e < E_DIM; ++e) { accn[e] = 0.f; accd[e] = 0.f; }

    // C_LEAF/BLOCK = 8 iterations; unroll x2 -> 12 dwordx4 loads in flight
#pragma unroll
    for (int it = 0; it < C_LEAF / BLOCK; it += 2) {
        const int c0 = it * BLOCK + threadIdx.x;
        const int c1 = c0 + BLOCK;
        const float x0 = xrow[c0];
        const float x1 = xrow[c1];
        const float4* __restrict__ n40 = (const float4*)(nrow + (size_t)c0 * E_DIM);
        const float4* __restrict__ d40 = (const float4*)(drow + (size_t)c0 * E_DIM);
        const float4* __restrict__ n41 = (const float4*)(nrow + (size_t)c1 * E_DIM);
        const float4* __restrict__ d41 = (const float4*)(drow + (size_t)c1 * E_DIM);
#pragma unroll
        for (int q = 0; q < 3; ++q) {
            const float4 nv0 = n40[q];
            const float4 dv0 = d40[q];
            const float4 nv1 = n41[q];
            const float4 dv1 = d41[q];
            accn[4*q+0] += x0 * nv0.x; accn[4*q+1] += x0 * nv0.y;
            accn[4*q+2] += x0 * nv0.z; accn[4*q+3] += x0 * nv0.w;
            accd[4*q+0] += x0 * dv0.x; accd[4*q+1] += x0 * dv0.y;
            accd[4*q+2] += x0 * dv0.z; accd[4*q+3] += x0 * dv0.w;
            accn[4*q+0] += x1 * nv1.x; accn[4*q+1] += x1 * nv1.y;
            accn[4*q+2] += x1 * nv1.z; accn[4*q+3] += x1 * nv1.w;
            accd[4*q+0] += x1 * dv1.x; accd[4*q+1] += x1 * dv1.y;
            accd[4*q+2] += x1 * dv1.z; accd[4*q+3] += x1 * dv1.w;
        }
    }

    // intra-wave butterfly reduction (wave = 64 lanes)
#pragma unroll
    for (int e = 0; e < E_DIM; ++e) {
#pragma unroll
        for (int off = 32; off >= 1; off >>= 1) {
            accn[e] += __shfl_xor(accn[e], off, 64);
            accd[e] += __shfl_xor(accd[e], off, 64);
        }
    }

    // cross-wave via LDS (4 waves)
    __shared__ float sn[4][E_DIM];
    __shared__ float sd[4][E_DIM];
    const int wave = threadIdx.x >> 6;
    const int lane = threadIdx.x & 63;
    if (lane == 0) {
#pragma unroll
        for (int e = 0; e < E_DIM; ++e) { sn[wave][e] = accn[e]; sd[wave][e] = accd[e]; }
    }
    __syncthreads();

    if (threadIdx.x == 0) {
        const float* __restrict__ w = weights + (size_t)t * E_DIM;
        float s = 0.f;
#pragma unroll
        for (int e = 0; e < E_DIM; ++e) {
            const float n = sn[0][e] + sn[1][e] + sn[2][e] + sn[3][e];
            const float d = sd[0][e] + sd[1][e] + sd[2][e] + sd[3][e];
            if (n != 0.f) s += w[e] * (-__logf(n / d));
        }
        per_sample[b] = s;   // plain store: no fences, no atomics
    }
}

// one wave; per_sample is [B], B multiple of 256 (=64 lanes x 4 float4)
__global__ __launch_bounds__(64) void hll_reduce_mean(
    const float* __restrict__ per_sample, float* __restrict__ out, int n)
{
    const float4* __restrict__ p4 = (const float4*)per_sample;
    const int n4 = n >> 2;
    float acc = 0.f;
    for (int i = threadIdx.x; i < n4; i += 64) {
        const float4 v = p4[i];
        acc += (v.x + v.y) + (v.z + v.w);
    }
#pragma unroll
    for (int off = 32; off >= 1; off >>= 1) acc += __shfl_xor(acc, off, 64);
    if (threadIdx.x == 0) out[0] = acc / (float)n;
}

extern "C" void kernel_launch(void* const* d_in, const int* in_sizes, int n_in,
                              void* d_out, int out_size, void* d_ws, size_t ws_size,
                              hipStream_t stream) {
    const float* inputs  = (const float*)d_in[0];
    const int*   target  = (const int*)  d_in[1];
    const float* onum    = (const float*)d_in[2];
    const float* oden    = (const float*)d_in[3];
    const float* weights = (const float*)d_in[4];
    float* out = (float*)d_out;

    const int B = in_sizes[1];           // target is [B]
    float* per_sample = (float*)d_ws;    // B floats of scratch

    hll_per_sample<<<B, BLOCK, 0, stream>>>(inputs, target, onum, oden, weights, per_sample);
    hll_reduce_mean<<<1, 64, 0, stream>>>(per_sample, out, B);
}

// Round 7
// 39.994 us; speedup vs baseline: 1.1600x; 1.1600x over previous
//
#include <hip/hip_runtime.h>

#define B_DEF      1024
#define C_LEAF     2048
#define E_DIM      12
#define BLOCK      256

__global__ __launch_bounds__(BLOCK) void hll_per_sample(
    const float* __restrict__ inputs,    // [B, C_LEAF]
    const int*   __restrict__ target,    // [B]
    const float* __restrict__ onum,      // [C_ALL, C_LEAF, E]
    const float* __restrict__ oden,      // [C_ALL, C_LEAF, E]
    const float* __restrict__ weights,   // [C_ALL, E]
    float*       __restrict__ per_sample // [B]
) {
    const int b = blockIdx.x;
    const int t = target[b];

    const float* __restrict__ xrow = inputs + (size_t)b * C_LEAF;
    const float* __restrict__ nrow = onum + (size_t)t * C_LEAF * E_DIM;
    const float* __restrict__ drow = oden + (size_t)t * C_LEAF * E_DIM;

    float accn[E_DIM], accd[E_DIM];
#pragma unroll
    for (int e = 0; e < E_DIM; ++e) { accn[e] = 0.f; accd[e] = 0.f; }

    for (int c = threadIdx.x; c < C_LEAF; c += BLOCK) {
        const float x = xrow[c];
        const float4* __restrict__ n4 = (const float4*)(nrow + (size_t)c * E_DIM);
        const float4* __restrict__ d4 = (const float4*)(drow + (size_t)c * E_DIM);
#pragma unroll
        for (int q = 0; q < 3; ++q) {
            const float4 nv = n4[q];
            const float4 dv = d4[q];
            accn[4*q+0] += x * nv.x; accn[4*q+1] += x * nv.y;
            accn[4*q+2] += x * nv.z; accn[4*q+3] += x * nv.w;
            accd[4*q+0] += x * dv.x; accd[4*q+1] += x * dv.y;
            accd[4*q+2] += x * dv.z; accd[4*q+3] += x * dv.w;
        }
    }

    // intra-wave butterfly reduction (wave = 64 lanes on CDNA)
#pragma unroll
    for (int e = 0; e < E_DIM; ++e) {
#pragma unroll
        for (int off = 32; off >= 1; off >>= 1) {
            accn[e] += __shfl_xor(accn[e], off, 64);
            accd[e] += __shfl_xor(accd[e], off, 64);
        }
    }

    // cross-wave via LDS (BLOCK/64 = 4 waves)
    __shared__ float sn[4][E_DIM];
    __shared__ float sd[4][E_DIM];
    const int wave = threadIdx.x >> 6;
    const int lane = threadIdx.x & 63;
    if (lane == 0) {
#pragma unroll
        for (int e = 0; e < E_DIM; ++e) { sn[wave][e] = accn[e]; sd[wave][e] = accd[e]; }
    }
    __syncthreads();

    if (threadIdx.x == 0) {
        const float* __restrict__ w = weights + (size_t)t * E_DIM;
        float s = 0.f;
#pragma unroll
        for (int e = 0; e < E_DIM; ++e) {
            const float n = sn[0][e] + sn[1][e] + sn[2][e] + sn[3][e];
            const float d = sd[0][e] + sd[1][e] + sd[2][e] + sd[3][e];
            if (n != 0.f) s += w[e] * (-__logf(n / d) );
        }
        per_sample[b] = s;
    }
}

__global__ __launch_bounds__(BLOCK) void hll_reduce_mean(
    const float* __restrict__ per_sample, float* __restrict__ out, int n)
{
    float acc = 0.f;
    for (int i = threadIdx.x; i < n; i += BLOCK) acc += per_sample[i];
#pragma unroll
    for (int off = 32; off >= 1; off >>= 1) acc += __shfl_xor(acc, off, 64);
    __shared__ float s[4];
    const int wave = threadIdx.x >> 6;
    const int lane = threadIdx.x & 63;
    if (lane == 0) s[wave] = acc;
    __syncthreads();
    if (threadIdx.x == 0) out[0] = (s[0] + s[1] + s[2] + s[3]) / (float)n;
}

extern "C" void kernel_launch(void* const* d_in, const int* in_sizes, int n_in,
                              void* d_out, int out_size, void* d_ws, size_t ws_size,
                              hipStream_t stream) {
    const float* inputs  = (const float*)d_in[0];
    const int*   target  = (const int*)  d_in[1];
    const float* onum    = (const float*)d_in[2];
    const float* oden    = (const float*)d_in[3];
    const float* weights = (const float*)d_in[4];
    float* out = (float*)d_out;

    const int B = in_sizes[1];           // target is [B]
    float* per_sample = (float*)d_ws;    // B floats of scratch

    hll_per_sample<<<B, BLOCK, 0, stream>>>(inputs, target, onum, oden, weights, per_sample);
    hll_reduce_mean<<<1, BLOCK, 0, stream>>>(per_sample, out, B);
}